// Round 1
// baseline (166.185 us; speedup 1.0000x reference)
//
#include <hip/hip_runtime.h>
#include <stdint.h>

#define N_DIM 4096
#define B_DIM 64

typedef __bf16 bf16x8 __attribute__((ext_vector_type(8)));
typedef float floatx4 __attribute__((ext_vector_type(4)));

union FragU { uint4 u; bf16x8 h; };

__device__ __forceinline__ unsigned short f2bf_rne(float f) {
    unsigned int u = __float_as_uint(f);
    u += 0x7fffu + ((u >> 16) & 1u);
    return (unsigned short)(u >> 16);
}

// c = Vmag*cos(ang), s = Vmag*sin(ang).
// fp32 copies in natural [b][j] layout (for epilogue),
// bf16 copies packed in MFMA B-fragment order: idx = ((j>>3)*64 + b)*8 + (j&7)
__global__ __launch_bounds__(256) void pf_prep(
        const float* __restrict__ Vmag, const float* __restrict__ Vang,
        unsigned short* __restrict__ c_pk, unsigned short* __restrict__ s_pk,
        float* __restrict__ c_f, float* __restrict__ s_f) {
    int idx = blockIdx.x * 256 + threadIdx.x;   // = b*4096 + j
    int b = idx >> 12;
    int j = idx & 4095;
    float sv, cv;
    sincosf(Vang[idx], &sv, &cv);
    float v = Vmag[idx];
    float c = v * cv;
    float s = v * sv;
    c_f[idx] = c;
    s_f[idx] = s;
    int p = (((j >> 3) << 6) + b) * 8 + (j & 7);
    c_pk[p] = f2bf_rne(c);
    s_pk[p] = f2bf_rne(s);
}

// One workgroup = 16 rows (i) of G/B, all 64 batches, 8 waves split K=4096
// into 512-element chunks. Wave tile: 16i x 64b, X and Y accumulators.
// X = G*c + B*s ; Y = G*s - B*c  (the -c via sign-bit XOR on the bf16 frag)
__global__ __launch_bounds__(512, 2) void pf_gemm(
        const float* __restrict__ G, const float* __restrict__ Bm,
        const unsigned short* __restrict__ c_pk, const unsigned short* __restrict__ s_pk,
        const float* __restrict__ c_f, const float* __restrict__ s_f,
        const float* __restrict__ P_in, const float* __restrict__ Q_in,
        float* __restrict__ out) {
    __shared__ float red[2][8][16][65];   // [X/Y][wave][m][b] (+1 pad vs conflicts)
    const int tid = threadIdx.x;
    const int wave = tid >> 6;
    const int lane = tid & 63;
    const int n = lane & 15;          // A: row index m ; B: col index b
    const int quad = lane >> 4;       // selects k-subgroup of 8
    const int i0 = blockIdx.x << 4;   // 16 rows per workgroup
    const int kw = wave << 9;         // wave's K-chunk start

    // A operand: G[i0+n][k], k = kw + quad*8 + (0..7), 8 contiguous fp32
    const float* gp = G  + (size_t)(i0 + n) * N_DIM + kw + (quad << 3);
    const float* bp = Bm + (size_t)(i0 + n) * N_DIM + kw + (quad << 3);
    // B operand: packed bf16, 8 contiguous per lane
    const unsigned short* cp = c_pk + ((size_t)(((kw >> 3) + quad) << 6) + n) * 8;
    const unsigned short* sp = s_pk + ((size_t)(((kw >> 3) + quad) << 6) + n) * 8;

    floatx4 accX[4], accY[4];
    #pragma unroll
    for (int t = 0; t < 4; ++t) {
        accX[t] = (floatx4){0.f, 0.f, 0.f, 0.f};
        accY[t] = (floatx4){0.f, 0.f, 0.f, 0.f};
    }

    // 16 iterations of K=32 per wave
    #pragma unroll 1
    for (int it = 0; it < 16; ++it) {
        float4 g0 = *(const float4*)gp;
        float4 g1 = *(const float4*)(gp + 4);
        float4 h0 = *(const float4*)bp;
        float4 h1 = *(const float4*)(bp + 4);
        uint4 cu[4], su[4];
        #pragma unroll
        for (int t = 0; t < 4; ++t) {
            cu[t] = *(const uint4*)(cp + t * 128);   // b-tile t: b += 16 -> +128 ushorts
            su[t] = *(const uint4*)(sp + t * 128);
        }
        gp += 32; bp += 32;           // k += 32
        cp += 2048; sp += 2048;       // 4 k-groups * 64 b * 8

        bf16x8 ag, ah;
        ag[0] = (__bf16)g0.x; ag[1] = (__bf16)g0.y; ag[2] = (__bf16)g0.z; ag[3] = (__bf16)g0.w;
        ag[4] = (__bf16)g1.x; ag[5] = (__bf16)g1.y; ag[6] = (__bf16)g1.z; ag[7] = (__bf16)g1.w;
        ah[0] = (__bf16)h0.x; ah[1] = (__bf16)h0.y; ah[2] = (__bf16)h0.z; ah[3] = (__bf16)h0.w;
        ah[4] = (__bf16)h1.x; ah[5] = (__bf16)h1.y; ah[6] = (__bf16)h1.z; ah[7] = (__bf16)h1.w;

        #pragma unroll
        for (int t = 0; t < 4; ++t) {
            FragU cf, sf, nf;
            cf.u = cu[t];
            sf.u = su[t];
            nf.u.x = cu[t].x ^ 0x80008000u;
            nf.u.y = cu[t].y ^ 0x80008000u;
            nf.u.z = cu[t].z ^ 0x80008000u;
            nf.u.w = cu[t].w ^ 0x80008000u;
            accX[t] = __builtin_amdgcn_mfma_f32_16x16x32_bf16(ag, cf.h, accX[t], 0, 0, 0);
            accX[t] = __builtin_amdgcn_mfma_f32_16x16x32_bf16(ah, sf.h, accX[t], 0, 0, 0);
            accY[t] = __builtin_amdgcn_mfma_f32_16x16x32_bf16(ag, sf.h, accY[t], 0, 0, 0);
            accY[t] = __builtin_amdgcn_mfma_f32_16x16x32_bf16(ah, nf.h, accY[t], 0, 0, 0);
        }
    }

    // cross-wave reduction: C/D layout is col(b)=lane&15, row(m)=quad*4+reg
    #pragma unroll
    for (int t = 0; t < 4; ++t) {
        #pragma unroll
        for (int r = 0; r < 4; ++r) {
            red[0][wave][(quad << 2) + r][(t << 4) + n] = accX[t][r];
            red[1][wave][(quad << 2) + r][(t << 4) + n] = accY[t][r];
        }
    }
    __syncthreads();

    // 1024 outputs (m,b) per workgroup; 512 threads -> 2 each; fused epilogue
    for (int e = tid; e < 1024; e += 512) {
        int bb = e >> 4;
        int m = e & 15;
        float X = 0.f, Y = 0.f;
        #pragma unroll
        for (int w = 0; w < 8; ++w) {
            X += red[0][w][m][bb];
            Y += red[1][w][m][bb];
        }
        size_t off = (size_t)bb * N_DIM + i0 + m;
        float c = c_f[off], s = s_f[off];
        out[off] = c * X + s * Y - P_in[off];                          // res_P
        out[(size_t)B_DIM * N_DIM + off] = s * X - c * Y - Q_in[off];  // res_Q
    }
}

extern "C" void kernel_launch(void* const* d_in, const int* in_sizes, int n_in,
                              void* d_out, int out_size, void* d_ws, size_t ws_size,
                              hipStream_t stream) {
    const float* Vmag = (const float*)d_in[0];
    const float* Vang = (const float*)d_in[1];
    const float* P_in = (const float*)d_in[2];
    const float* Q_in = (const float*)d_in[3];
    const float* G    = (const float*)d_in[4];
    const float* Bm   = (const float*)d_in[5];
    float* out = (float*)d_out;

    char* ws = (char*)d_ws;
    unsigned short* c_pk = (unsigned short*)(ws);                    // 512 KB
    unsigned short* s_pk = (unsigned short*)(ws + (512u << 10));     // 512 KB
    float* c_f = (float*)(ws + (1u << 20));                          // 1 MB
    float* s_f = (float*)(ws + (2u << 20));                          // 1 MB

    hipLaunchKernelGGL(pf_prep, dim3((B_DIM * N_DIM) / 256), dim3(256), 0, stream,
                       Vmag, Vang, c_pk, s_pk, c_f, s_f);
    hipLaunchKernelGGL(pf_gemm, dim3(N_DIM / 16), dim3(512), 0, stream,
                       G, Bm, c_pk, s_pk, c_f, s_f, P_in, Q_in, out);
}